// Round 5
// baseline (87.550 us; speedup 1.0000x reference)
//
#include <hip/hip_runtime.h>
#include <hip/hip_bf16.h>

// PointPillarScatter: out[1, C, NY, NX] (fp32), zero except
// out[c, y, x] = pillar_features[c, p] for pillar p at (z=0, y, x).
// C=64, NX=NY=1024, P=100000.
//   d_in[0]: pillar_features float32 [C, P]
//   d_in[1]: coords int32 [1, P, 3] (z, y, x)
//
// Inverse-map + full-coverage gather (every output element written exactly
// once, coalesced NT float4). Round 5: CPT=8 + explicit two-phase gather
// (issue all 32 predicated random loads, then all 8 coalesced stores) to
// deepen the memory pipeline per wave.

constexpr int C_CH   = 64;
constexpr int NX_G   = 1024;
constexpr int NY_G   = 1024;
constexpr int NCELLS = NX_G * NY_G;
constexpr int QUADS  = NCELLS / 4;      // 262144 = 2^18
constexpr int CPT    = 8;               // channels per thread
constexpr int GROUPS = C_CH / CPT;      // 8

typedef __attribute__((ext_vector_type(4))) float f32x4;

__global__ void pp_fill_map(int4* __restrict__ map) {
    int t = blockIdx.x * blockDim.x + threadIdx.x;
    map[t] = make_int4(-1, -1, -1, -1);
}

__global__ void pp_build_map(const int* __restrict__ coords,
                             int* __restrict__ map, int P) {
    int p = blockIdx.x * blockDim.x + threadIdx.x;
    if (p >= P) return;
    int z = coords[3 * p + 0];
    int y = coords[3 * p + 1];
    int x = coords[3 * p + 2];
    map[z + y * NX_G + x] = p;
}

__global__ __launch_bounds__(256)
void pp_gather(const float* __restrict__ pf,
               const int* __restrict__ map,
               float* __restrict__ out, int P) {
    int t = blockIdx.x * blockDim.x + threadIdx.x;  // [0, GROUPS*QUADS)
    int q = t & (QUADS - 1);    // quad-cell id -> coalesced map load + store
    int g = t >> 18;            // channel group
    const int4 pid = reinterpret_cast<const int4*>(map)[q];
    const int cbase = g * CPT;

    f32x4 v[CPT];
    // Phase 1: issue all predicated random loads (independent, deep pipeline).
#pragma unroll
    for (int i = 0; i < CPT; ++i) {
        const float* __restrict__ pfc = pf + (size_t)(cbase + i) * P;
        v[i].x = (pid.x >= 0) ? pfc[pid.x] : 0.0f;
        v[i].y = (pid.y >= 0) ? pfc[pid.y] : 0.0f;
        v[i].z = (pid.z >= 0) ? pfc[pid.z] : 0.0f;
        v[i].w = (pid.w >= 0) ? pfc[pid.w] : 0.0f;
    }
    // Phase 2: coalesced nontemporal stores (write-once stream, keep L2 for pf/map).
#pragma unroll
    for (int i = 0; i < CPT; ++i) {
        f32x4* dst = reinterpret_cast<f32x4*>(out + (size_t)(cbase + i) * NCELLS) + q;
        __builtin_nontemporal_store(v[i], dst);
    }
}

extern "C" void kernel_launch(void* const* d_in, const int* in_sizes, int n_in,
                              void* d_out, int out_size, void* d_ws, size_t ws_size,
                              hipStream_t stream) {
    const float* pf     = (const float*)d_in[0];
    const int*   coords = (const int*)d_in[1];
    float*       out    = (float*)d_out;
    int*         map    = (int*)d_ws;  // NCELLS ints = 4 MiB

    const int P = in_sizes[0] / C_CH;  // 100000

    pp_fill_map<<<QUADS / 256, 256, 0, stream>>>((int4*)map);
    pp_build_map<<<(P + 255) / 256, 256, 0, stream>>>(coords, map, P);

    const int threads = GROUPS * QUADS;  // 2,097,152
    pp_gather<<<threads / 256, 256, 0, stream>>>(pf, map, out, P);
}

// Round 6
// 72.380 us; speedup vs baseline: 1.2096x; 1.2096x over previous
//
#include <hip/hip_runtime.h>
#include <hip/hip_bf16.h>

// PointPillarScatter: out[1, C, NY, NX] (fp32), zero except
// out[c, y, x] = pillar_features[c, p] for pillar p at (z=0, y, x).
// C=64, NX=NY=1024, P=100000.
//   d_in[0]: pillar_features float32 [C, P]
//   d_in[1]: coords int32 [1, P, 3] (z, y, x)
//
// Round 6: inverse-map + pf transpose to [P, 64] (one pillar's channels
// contiguous) so the full-coverage gather does ONE float4 random load per
// cell per 4-channel group (was 4 scalar loads 400 KB apart). 4x fewer
// random transactions, full 64B-line utilization. CPT=4 (round-4 winner).

constexpr int C_CH   = 64;
constexpr int NX_G   = 1024;
constexpr int NY_G   = 1024;
constexpr int NCELLS = NX_G * NY_G;
constexpr int QUADS  = NCELLS / 4;      // 262144 = 2^18
constexpr int GROUPS = 16;              // channel groups of 4

typedef __attribute__((ext_vector_type(4))) float f32x4;

__global__ void pp_fill_map(int4* __restrict__ map) {
    int t = blockIdx.x * blockDim.x + threadIdx.x;
    map[t] = make_int4(-1, -1, -1, -1);
}

// Transpose pf [64, P] -> pfT [P, 64]; also build the cell->pillar map.
__global__ __launch_bounds__(256)
void pp_transpose_buildmap(const float* __restrict__ pf,
                           const int* __restrict__ coords,
                           float* __restrict__ pfT,
                           int* __restrict__ map, int P) {
    __shared__ float tile[64][65];   // +1 pad
    const int pbase = blockIdx.x * 64;
    const int lane  = threadIdx.x & 63;
    const int row4  = threadIdx.x >> 6;   // 0..3
    const int p     = pbase + lane;
    const bool pin  = (p < P);

    // Load 64 channels x 64 pillars, coalesced along P.
#pragma unroll
    for (int r = 0; r < 16; ++r) {
        int c = (r << 2) + row4;
        tile[c][lane] = pin ? pf[(size_t)c * P + p] : 0.0f;
    }

    // Fold in build_map: first 64 threads handle this block's pillars.
    if (threadIdx.x < 64 && pin) {
        int z = coords[3 * p + 0];
        int y = coords[3 * p + 1];
        int x = coords[3 * p + 2];
        map[z + y * NX_G + x] = p;
    }
    __syncthreads();

    // Write pfT rows: thread t -> pillar j = t>>2, channels (t&3)*16 .. +15.
    const int j  = threadIdx.x >> 2;
    const int c0 = (threadIdx.x & 3) << 4;
    if (pbase + j < P) {
        float* dst = pfT + (size_t)(pbase + j) * 64 + c0;
#pragma unroll
        for (int k = 0; k < 16; k += 4) {
            f32x4 v = { tile[c0 + k][j], tile[c0 + k + 1][j],
                        tile[c0 + k + 2][j], tile[c0 + k + 3][j] };
            *reinterpret_cast<f32x4*>(dst + k) = v;
        }
    }
}

__global__ __launch_bounds__(256)
void pp_gather(const float* __restrict__ pfT,
               const int* __restrict__ map,
               float* __restrict__ out) {
    int t = blockIdx.x * blockDim.x + threadIdx.x;  // [0, GROUPS*QUADS)
    int q = t & (QUADS - 1);    // quad-cell id -> coalesced map load + store
    int g = t >> 18;            // channel group (0..15)
    const int4 pid = reinterpret_cast<const int4*>(map)[q];
    const int c0 = g << 2;

    f32x4 a = {0,0,0,0}, b = {0,0,0,0}, c = {0,0,0,0}, d = {0,0,0,0};
    if (pid.x >= 0) a = *reinterpret_cast<const f32x4*>(pfT + ((size_t)pid.x << 6) + c0);
    if (pid.y >= 0) b = *reinterpret_cast<const f32x4*>(pfT + ((size_t)pid.y << 6) + c0);
    if (pid.z >= 0) c = *reinterpret_cast<const f32x4*>(pfT + ((size_t)pid.z << 6) + c0);
    if (pid.w >= 0) d = *reinterpret_cast<const f32x4*>(pfT + ((size_t)pid.w << 6) + c0);

    // 4x4 in-register transpose: channel c0+i gets {a[i], b[i], c[i], d[i]}.
#pragma unroll
    for (int i = 0; i < 4; ++i) {
        f32x4 v = { a[i], b[i], c[i], d[i] };
        f32x4* dst = reinterpret_cast<f32x4*>(out + (size_t)(c0 + i) * NCELLS) + q;
        __builtin_nontemporal_store(v, dst);
    }
}

extern "C" void kernel_launch(void* const* d_in, const int* in_sizes, int n_in,
                              void* d_out, int out_size, void* d_ws, size_t ws_size,
                              hipStream_t stream) {
    const float* pf     = (const float*)d_in[0];
    const int*   coords = (const int*)d_in[1];
    float*       out    = (float*)d_out;
    int*         map    = (int*)d_ws;                       // 4 MiB
    float*       pfT    = (float*)((char*)d_ws + (size_t)NCELLS * sizeof(int)); // 25.6 MB

    const int P = in_sizes[0] / C_CH;  // 100000

    pp_fill_map<<<QUADS / 256, 256, 0, stream>>>((int4*)map);

    const int tblocks = (P + 63) / 64;  // 1563
    pp_transpose_buildmap<<<tblocks, 256, 0, stream>>>(pf, coords, pfT, map, P);

    const int threads = GROUPS * QUADS;  // 4,194,304
    pp_gather<<<threads / 256, 256, 0, stream>>>(pfT, map, out);
}